// Round 4
// baseline (54.440 us; speedup 1.0000x reference)
//
#include <hip/hip_runtime.h>
#include <math.h>

#define NT 512
#define WAVES (NT / 64)
#define T_DIM 2048
#define B_DIM 1024
#define CHUNK 4              // timesteps per thread

typedef float f4 __attribute__((ext_vector_type(4)));
typedef int   i4 __attribute__((ext_vector_type(4)));

// Wave64 inclusive scan of a float2 (component-wise).
__device__ inline float2 wave_incl_scan(float2 v, int lane) {
  #pragma unroll
  for (int d = 1; d < 64; d <<= 1) {
    float ax = __shfl_up(v.x, d, 64);
    float ay = __shfl_up(v.y, d, 64);
    if (lane >= d) { v.x += ax; v.y += ay; }
  }
  return v;
}

// One block per batch row; fused final reduction via last-block pattern.
__global__ __launch_bounds__(NT) void path_loss_fused(
    const float* __restrict__ outs,
    const int*   __restrict__ labels,
    float*       __restrict__ partial,
    unsigned*    __restrict__ counter,
    float*       __restrict__ out)
{
  // 40960 B staging buffer; scratch regions alias it after staging reads.
  __shared__ alignas(16) unsigned char lds_raw[40960];
  f4*     stage  = (f4*)lds_raw;                  // 2560 float4 = whole row
  int*    amLast = (int*)lds_raw;                 // [0,4)
  float2* wsum   = (float2*)(lds_raw + 16);       // [16,80)
  float2* wsum2  = (float2*)(lds_raw + 80);       // [80,144)
  float*  rsum   = (float*)(lds_raw + 144);       // [144,176)
  double* rb     = (double*)(lds_raw + 256);      // [256,320)

  const int tid  = threadIdx.x;
  const int lane = tid & 63;
  const int wid  = tid >> 6;
  const int b    = blockIdx.x;

  // ---- coalesced stage: 5 sweeps of lane-consecutive float4 (cached loads) ----
  const f4* rowO4 = (const f4*)(outs + (size_t)b * T_DIM * 5);
  #pragma unroll
  for (int j = 0; j < 5; ++j)
    stage[j * NT + tid] = rowO4[j * NT + tid];

  // labels: lane-consecutive int4 (already coalesced)
  i4 lv = ((const i4*)(labels + (size_t)b * T_DIM))[tid];
  int lbl[CHUNK] = { lv[0], lv[1], lv[2], lv[3] };

  __syncthreads();                                 // staging visible

  // ---- each thread reads its 20 floats (tid*80B .. +80B) from LDS ----
  // bank pattern: 20i mod 32 cycles through 8 distinct 4-dword slots per
  // 8 lanes -> all 32 banks covered, conflict-free b128 reads.
  float vals[20];
  #pragma unroll
  for (int j = 0; j < 5; ++j) {
    f4 v = stage[tid * 5 + j];
    vals[4*j+0] = v[0]; vals[4*j+1] = v[1]; vals[4*j+2] = v[2]; vals[4*j+3] = v[3];
  }

  const float WT = 1.0f / (1.0f + 1e-6f);
  float dthP[CHUNK], fwP[CHUNK], dthT[CHUNK], fwT[CHUNK];
  #pragma unroll
  for (int k = 0; k < CHUNK; ++k) {
    float o0 = vals[5*k+0], o1 = vals[5*k+1], o2 = vals[5*k+2],
          o3 = vals[5*k+3], o4 = vals[5*k+4];
    float m = o0; int am = 0;                      // first-occurrence argmax
    if (o1 > m) { m = o1; am = 1; }
    if (o2 > m) { m = o2; am = 2; }
    if (o3 > m) { m = o3; am = 3; }
    if (o4 > m) { m = o4; am = 4; }
    float sum = __expf(o0-m) + __expf(o1-m) + __expf(o2-m)
              + __expf(o3-m) + __expf(o4-m);
    float s = 1.0f / sum;
    float w = s / (s + 1e-6f);
    float sgn = (am==1 || am==3) ? 1.0f : ((am==2 || am==4) ? -1.0f : 0.0f);
    fwP[k]  = (am==0 || am==3 || am==4) ? w : 0.0f;
    dthP[k] = 0.15f * sgn * w;

    int l = lbl[k];
    float sgt = (l==1 || l==3) ? 1.0f : ((l==2 || l==4) ? -1.0f : 0.0f);
    fwT[k]  = (l==0 || l==3 || l==4) ? WT : 0.0f;
    dthT[k] = 0.15f * sgt * WT;
  }

  // ================= scan 1: exclusive prefix of dth ====================
  float2 csum = make_float2(0.f, 0.f);
  #pragma unroll
  for (int k = 0; k < CHUNK; ++k) { csum.x += dthP[k]; csum.y += dthT[k]; }

  float2 incl = wave_incl_scan(csum, lane);
  __syncthreads();                                 // staging reads done -> scratch OK
  if (lane == 63) wsum[wid] = incl;
  __syncthreads();
  float2 base = make_float2(0.f, 0.f);
  #pragma unroll
  for (int w = 0; w < WAVES; ++w) {
    float2 t = wsum[w];
    if (w < wid) { base.x += t.x; base.y += t.y; }
  }
  float ex = __shfl_up(incl.x, 1, 64);
  float ey = __shfl_up(incl.y, 1, 64);
  float thP = base.x + ((lane == 0) ? 0.f : ex);
  float thT = base.y + ((lane == 0) ? 0.f : ey);

  // ---- contributions c = fw * cos(theta); theta read before update ----
  float cP[CHUNK], cT[CHUNK];
  float2 xsum = make_float2(0.f, 0.f);
  #pragma unroll
  for (int k = 0; k < CHUNK; ++k) {
    cP[k] = fwP[k] * __cosf(thP);                  // |theta| <= ~307 rad, in v_cos range
    cT[k] = fwT[k] * __cosf(thT);
    thP += dthP[k]; thT += dthT[k];
    xsum.x += cP[k]; xsum.y += cT[k];
  }

  // ================= scan 2: inclusive prefix of c ======================
  float2 incl2 = wave_incl_scan(xsum, lane);
  if (lane == 63) wsum2[wid] = incl2;              // distinct region, no hazard w/ wsum reads
  __syncthreads();
  float2 base2 = make_float2(0.f, 0.f);
  #pragma unroll
  for (int w = 0; w < WAVES; ++w) {
    float2 t = wsum2[w];
    if (w < wid) { base2.x += t.x; base2.y += t.y; }
  }
  float ex2 = __shfl_up(incl2.x, 1, 64);
  float ey2 = __shfl_up(incl2.y, 1, 64);
  float xP = base2.x + ((lane == 0) ? 0.f : ex2);
  float xT = base2.y + ((lane == 0) ? 0.f : ey2);

  // ---- loss terms ----
  float acc = 0.f;
  #pragma unroll
  for (int k = 0; k < CHUNK; ++k) {
    xP += cP[k]; xT += cT[k];
    float dx = xP - xT;
    acc += sqrtf(2.0f * dx * dx + 1e-12f);
  }

  // ---- block reduce ----
  #pragma unroll
  for (int d = 32; d > 0; d >>= 1) acc += __shfl_down(acc, d, 64);
  if (lane == 0) rsum[wid] = acc;
  __syncthreads();

  if (tid == 0) {
    float s = 0.f;
    #pragma unroll
    for (int w = 0; w < WAVES; ++w) s += rsum[w];
    __hip_atomic_store(&partial[b], s, __ATOMIC_RELEASE, __HIP_MEMORY_SCOPE_AGENT);
    unsigned prev = __hip_atomic_fetch_add(counter, 1u, __ATOMIC_ACQ_REL,
                                           __HIP_MEMORY_SCOPE_AGENT);
    *amLast = (prev == B_DIM - 1u) ? 1 : 0;
  }
  __syncthreads();

  // ---- last block: deterministic fixed-order final reduction ----
  if (*amLast) {
    double v = (double)__hip_atomic_load(&partial[tid], __ATOMIC_ACQUIRE,
                                         __HIP_MEMORY_SCOPE_AGENT)
             + (double)__hip_atomic_load(&partial[tid + NT], __ATOMIC_ACQUIRE,
                                         __HIP_MEMORY_SCOPE_AGENT);
    #pragma unroll
    for (int d = 32; d > 0; d >>= 1) v += __shfl_down(v, d, 64);
    if (lane == 0) rb[wid] = v;
    __syncthreads();
    if (tid == 0) {
      double tot = 0.0;
      #pragma unroll
      for (int w = 0; w < WAVES; ++w) tot += rb[w];
      tot += (double)B_DIM * 1e-6;                 // t=0 column: sqrt(1e-12) per row
      out[0] = (float)(tot / ((double)B_DIM * (double)(T_DIM + 1)));
    }
  }
}

extern "C" void kernel_launch(void* const* d_in, const int* in_sizes, int n_in,
                              void* d_out, int out_size, void* d_ws, size_t ws_size,
                              hipStream_t stream) {
  const float* outs   = (const float*)d_in[0];
  const int*   labels = (const int*)d_in[1];
  float*    partial = (float*)d_ws;
  unsigned* counter = (unsigned*)((char*)d_ws + 8192);
  float*    out     = (float*)d_out;

  hipMemsetAsync(counter, 0, sizeof(unsigned), stream);   // capture-safe
  path_loss_fused<<<B_DIM, NT, 0, stream>>>(outs, labels, partial, counter, out);
}

// Round 5
// 19.300 us; speedup vs baseline: 2.8207x; 2.8207x over previous
//
#include <hip/hip_runtime.h>
#include <math.h>

#define NT 512
#define WAVES (NT / 64)
#define T_DIM 2048
#define B_DIM 1024
#define CHUNK 4              // timesteps per thread

typedef float f4 __attribute__((ext_vector_type(4)));
typedef int   i4 __attribute__((ext_vector_type(4)));

// Wave64 inclusive scan of a float2 (component-wise).
__device__ inline float2 wave_incl_scan(float2 v, int lane) {
  #pragma unroll
  for (int d = 1; d < 64; d <<= 1) {
    float ax = __shfl_up(v.x, d, 64);
    float ay = __shfl_up(v.y, d, 64);
    if (lane >= d) { v.x += ax; v.y += ay; }
  }
  return v;
}

// One block per batch row. Coalesced LDS staging + wave-shuffle scans.
// Plain partial store at the end -- NO atomics, NO fences.
__global__ __launch_bounds__(NT) void path_loss_rows(
    const float* __restrict__ outs,
    const int*   __restrict__ labels,
    float*       __restrict__ partial)
{
  // 40960 B staging buffer; small scratch regions alias it after staging reads.
  __shared__ alignas(16) unsigned char lds_raw[40960];
  f4*     stage  = (f4*)lds_raw;                  // 2560 float4 = whole row
  float2* wsum   = (float2*)(lds_raw);            // [0,64)
  float2* wsum2  = (float2*)(lds_raw + 64);       // [64,128)
  float*  rsum   = (float*)(lds_raw + 128);       // [128,160)

  const int tid  = threadIdx.x;
  const int lane = tid & 63;
  const int wid  = tid >> 6;
  const int b    = blockIdx.x;

  // ---- coalesced stage: 5 sweeps of lane-consecutive float4 (cached) ----
  const f4* rowO4 = (const f4*)(outs + (size_t)b * T_DIM * 5);
  #pragma unroll
  for (int j = 0; j < 5; ++j)
    stage[j * NT + tid] = rowO4[j * NT + tid];

  // labels: lane-consecutive int4 (already coalesced)
  i4 lv = ((const i4*)(labels + (size_t)b * T_DIM))[tid];
  int lbl[CHUNK] = { lv[0], lv[1], lv[2], lv[3] };

  __syncthreads();                                 // staging visible

  // ---- each thread reads its 20 floats (tid*80B .. +80B) from LDS ----
  float vals[20];
  #pragma unroll
  for (int j = 0; j < 5; ++j) {
    f4 v = stage[tid * 5 + j];
    vals[4*j+0] = v[0]; vals[4*j+1] = v[1]; vals[4*j+2] = v[2]; vals[4*j+3] = v[3];
  }

  const float WT = 1.0f / (1.0f + 1e-6f);
  float dthP[CHUNK], fwP[CHUNK], dthT[CHUNK], fwT[CHUNK];
  #pragma unroll
  for (int k = 0; k < CHUNK; ++k) {
    float o0 = vals[5*k+0], o1 = vals[5*k+1], o2 = vals[5*k+2],
          o3 = vals[5*k+3], o4 = vals[5*k+4];
    float m = o0; int am = 0;                      // first-occurrence argmax
    if (o1 > m) { m = o1; am = 1; }
    if (o2 > m) { m = o2; am = 2; }
    if (o3 > m) { m = o3; am = 3; }
    if (o4 > m) { m = o4; am = 4; }
    float sum = __expf(o0-m) + __expf(o1-m) + __expf(o2-m)
              + __expf(o3-m) + __expf(o4-m);
    float s = 1.0f / sum;
    float w = s / (s + 1e-6f);
    float sgn = (am==1 || am==3) ? 1.0f : ((am==2 || am==4) ? -1.0f : 0.0f);
    fwP[k]  = (am==0 || am==3 || am==4) ? w : 0.0f;
    dthP[k] = 0.15f * sgn * w;

    int l = lbl[k];
    float sgt = (l==1 || l==3) ? 1.0f : ((l==2 || l==4) ? -1.0f : 0.0f);
    fwT[k]  = (l==0 || l==3 || l==4) ? WT : 0.0f;
    dthT[k] = 0.15f * sgt * WT;
  }

  // ================= scan 1: exclusive prefix of dth ====================
  float2 csum = make_float2(0.f, 0.f);
  #pragma unroll
  for (int k = 0; k < CHUNK; ++k) { csum.x += dthP[k]; csum.y += dthT[k]; }

  float2 incl = wave_incl_scan(csum, lane);
  __syncthreads();                                 // staging reads done -> scratch OK
  if (lane == 63) wsum[wid] = incl;
  __syncthreads();
  float2 base = make_float2(0.f, 0.f);
  #pragma unroll
  for (int w = 0; w < WAVES; ++w) {
    float2 t = wsum[w];
    if (w < wid) { base.x += t.x; base.y += t.y; }
  }
  float ex = __shfl_up(incl.x, 1, 64);
  float ey = __shfl_up(incl.y, 1, 64);
  float thP = base.x + ((lane == 0) ? 0.f : ex);
  float thT = base.y + ((lane == 0) ? 0.f : ey);

  // ---- contributions c = fw * cos(theta); theta read before update ----
  float cP[CHUNK], cT[CHUNK];
  float2 xsum = make_float2(0.f, 0.f);
  #pragma unroll
  for (int k = 0; k < CHUNK; ++k) {
    cP[k] = fwP[k] * __cosf(thP);                  // |theta| <= ~307 rad, in v_cos range
    cT[k] = fwT[k] * __cosf(thT);
    thP += dthP[k]; thT += dthT[k];
    xsum.x += cP[k]; xsum.y += cT[k];
  }

  // ================= scan 2: inclusive prefix of c ======================
  float2 incl2 = wave_incl_scan(xsum, lane);
  if (lane == 63) wsum2[wid] = incl2;              // distinct region from wsum
  __syncthreads();
  float2 base2 = make_float2(0.f, 0.f);
  #pragma unroll
  for (int w = 0; w < WAVES; ++w) {
    float2 t = wsum2[w];
    if (w < wid) { base2.x += t.x; base2.y += t.y; }
  }
  float ex2 = __shfl_up(incl2.x, 1, 64);
  float ey2 = __shfl_up(incl2.y, 1, 64);
  float xP = base2.x + ((lane == 0) ? 0.f : ex2);
  float xT = base2.y + ((lane == 0) ? 0.f : ey2);

  // ---- loss terms ----
  float acc = 0.f;
  #pragma unroll
  for (int k = 0; k < CHUNK; ++k) {
    xP += cP[k]; xT += cT[k];
    float dx = xP - xT;
    acc += sqrtf(2.0f * dx * dx + 1e-12f);
  }

  // ---- block reduce ----
  #pragma unroll
  for (int d = 32; d > 0; d >>= 1) acc += __shfl_down(acc, d, 64);
  if (lane == 0) rsum[wid] = acc;
  __syncthreads();
  if (tid == 0) {
    float s = 0.f;
    #pragma unroll
    for (int w = 0; w < WAVES; ++w) s += rsum[w];
    partial[b] = s;                                // plain store
  }
}

__global__ __launch_bounds__(256) void path_loss_reduce(
    const float* __restrict__ partial, float* __restrict__ out)
{
  __shared__ double rb[4];
  const int tid = threadIdx.x, lane = tid & 63, wid = tid >> 6;
  f4 v = ((const f4*)partial)[tid];                // 256*4 = 1024 floats
  double s = (double)v[0] + (double)v[1] + (double)v[2] + (double)v[3];
  #pragma unroll
  for (int d = 32; d > 0; d >>= 1) s += __shfl_down(s, d, 64);
  if (lane == 0) rb[wid] = s;
  __syncthreads();
  if (tid == 0) {
    double tot = rb[0] + rb[1] + rb[2] + rb[3];
    tot += (double)B_DIM * 1e-6;                   // t=0 column: sqrt(1e-12) per row
    out[0] = (float)(tot / ((double)B_DIM * (double)(T_DIM + 1)));
  }
}

extern "C" void kernel_launch(void* const* d_in, const int* in_sizes, int n_in,
                              void* d_out, int out_size, void* d_ws, size_t ws_size,
                              hipStream_t stream) {
  const float* outs   = (const float*)d_in[0];
  const int*   labels = (const int*)d_in[1];
  float* partial = (float*)d_ws;
  float* out     = (float*)d_out;

  path_loss_rows<<<B_DIM, NT, 0, stream>>>(outs, labels, partial);
  path_loss_reduce<<<1, 256, 0, stream>>>(partial, out);
}

// Round 6
// 16.283 us; speedup vs baseline: 3.3433x; 1.1853x over previous
//
#include <hip/hip_runtime.h>
#include <math.h>

#define NT 512
#define WAVES (NT / 64)
#define T_DIM 2048
#define B_DIM 1024
#define CHUNK 4              // timesteps per thread

typedef float f4 __attribute__((ext_vector_type(4)));
typedef int   i4 __attribute__((ext_vector_type(4)));

__device__ __forceinline__ int   biti(float x) { return __builtin_bit_cast(int, x); }
__device__ __forceinline__ float bitf(int x)   { return __builtin_bit_cast(float, x); }

// Wave64 inclusive add-scan, pure VALU via DPP (no DS-pipe traffic).
// row_shr:1/2/4/8 within 16-lane rows, then row_bcast15 (rows 1,3) and
// row_bcast31 (rows 2,3). old=0 so masked/invalid lanes add 0.
__device__ __forceinline__ float wave_scan_dpp(float x) {
  x += bitf(__builtin_amdgcn_update_dpp(0, biti(x), 0x111, 0xf, 0xf, false));
  x += bitf(__builtin_amdgcn_update_dpp(0, biti(x), 0x112, 0xf, 0xf, false));
  x += bitf(__builtin_amdgcn_update_dpp(0, biti(x), 0x114, 0xf, 0xf, false));
  x += bitf(__builtin_amdgcn_update_dpp(0, biti(x), 0x118, 0xf, 0xf, false));
  x += bitf(__builtin_amdgcn_update_dpp(0, biti(x), 0x142, 0xa, 0xf, false));
  x += bitf(__builtin_amdgcn_update_dpp(0, biti(x), 0x143, 0xc, 0xf, false));
  return x;
}

// One block per batch row. Direct coalesced-enough loads (proven neutral vs
// LDS staging), DPP scans, plain partial store (no atomics / fences).
__global__ __launch_bounds__(NT) void path_loss_rows(
    const float* __restrict__ outs,
    const int*   __restrict__ labels,
    float*       __restrict__ partial)
{
  __shared__ float2 wsum[WAVES];
  __shared__ float2 wsum2[WAVES];
  __shared__ float  rsum[WAVES];

  const int tid  = threadIdx.x;
  const int lane = tid & 63;
  const int wid  = tid >> 6;
  const int b    = blockIdx.x;
  const int t0   = tid * CHUNK;

  const float* rowO = outs   + (size_t)b * T_DIM * 5;
  const int*   rowL = labels + (size_t)b * T_DIM;

  // ---- 20 floats (5x float4, 16B-aligned: tid*80B) + 4 labels ----
  float vals[20];
  const f4* vp = (const f4*)(rowO + (size_t)t0 * 5);
  #pragma unroll
  for (int j = 0; j < 5; ++j) {
    f4 v = vp[j];
    vals[4*j+0] = v[0]; vals[4*j+1] = v[1]; vals[4*j+2] = v[2]; vals[4*j+3] = v[3];
  }
  i4 lv = ((const i4*)rowL)[tid];
  int lbl[CHUNK] = { lv[0], lv[1], lv[2], lv[3] };

  const float WT = (float)(1.0 / (1.0 + 1e-6));
  float dthP[CHUNK], fwP[CHUNK], dthT[CHUNK], fwT[CHUNK];
  #pragma unroll
  for (int k = 0; k < CHUNK; ++k) {
    float o0 = vals[5*k+0], o1 = vals[5*k+1], o2 = vals[5*k+2],
          o3 = vals[5*k+3], o4 = vals[5*k+4];
    float m = o0; int am = 0;                      // first-occurrence argmax
    if (o1 > m) { m = o1; am = 1; }
    if (o2 > m) { m = o2; am = 2; }
    if (o3 > m) { m = o3; am = 3; }
    if (o4 > m) { m = o4; am = 4; }
    float sum = __expf(o0-m) + __expf(o1-m) + __expf(o2-m)
              + __expf(o3-m) + __expf(o4-m);
    // w = s/(s+1e-6) with s=1/sum  ==  1/(1 + 1e-6*sum): one fast rcp
    float w = __builtin_amdgcn_rcpf(1.0f + 1e-6f * sum);
    float w15 = 0.15f * w;
    fwP[k]  = (am==0 || am==3 || am==4) ? w : 0.0f;
    dthP[k] = (am==1 || am==3) ? w15 : ((am==2 || am==4) ? -w15 : 0.0f);

    int l = lbl[k];
    fwT[k]  = (l==0 || l==3 || l==4) ? WT : 0.0f;
    dthT[k] = (l==1 || l==3) ? 0.15f*WT : ((l==2 || l==4) ? -0.15f*WT : 0.0f);
  }

  // ================= scan 1: exclusive prefix of dth ====================
  float2 csum = make_float2(0.f, 0.f);
  #pragma unroll
  for (int k = 0; k < CHUNK; ++k) { csum.x += dthP[k]; csum.y += dthT[k]; }

  float ix = wave_scan_dpp(csum.x);
  float iy = wave_scan_dpp(csum.y);
  if (lane == 63) wsum[wid] = make_float2(ix, iy);
  __syncthreads();
  float2 base = make_float2(0.f, 0.f);
  #pragma unroll
  for (int w = 0; w < WAVES; ++w) {
    float2 t = wsum[w];
    if (w < wid) { base.x += t.x; base.y += t.y; }
  }
  float thP = base.x + (ix - csum.x);              // exclusive = incl - own
  float thT = base.y + (iy - csum.y);

  // ---- contributions c = fw * cos(theta); theta read before update ----
  float cP[CHUNK], cT[CHUNK];
  float2 xsum = make_float2(0.f, 0.f);
  #pragma unroll
  for (int k = 0; k < CHUNK; ++k) {
    cP[k] = fwP[k] * __cosf(thP);                  // |theta| <= ~307 rad, in range
    cT[k] = fwT[k] * __cosf(thT);
    thP += dthP[k]; thT += dthT[k];
    xsum.x += cP[k]; xsum.y += cT[k];
  }

  // ================= scan 2: inclusive prefix of c ======================
  float jx = wave_scan_dpp(xsum.x);
  float jy = wave_scan_dpp(xsum.y);
  if (lane == 63) wsum2[wid] = make_float2(jx, jy);
  __syncthreads();
  float2 base2 = make_float2(0.f, 0.f);
  #pragma unroll
  for (int w = 0; w < WAVES; ++w) {
    float2 t = wsum2[w];
    if (w < wid) { base2.x += t.x; base2.y += t.y; }
  }
  float xP = base2.x + (jx - xsum.x);
  float xT = base2.y + (jy - xsum.y);

  // ---- loss terms ----
  float acc = 0.f;
  #pragma unroll
  for (int k = 0; k < CHUNK; ++k) {
    xP += cP[k]; xT += cT[k];
    float dx = xP - xT;
    acc += __builtin_amdgcn_sqrtf(2.0f * dx * dx + 1e-12f);
  }

  // ---- block reduce: DPP scan total (lane 63) + 8-entry combine ----
  float atot = wave_scan_dpp(acc);
  if (lane == 63) rsum[wid] = atot;
  __syncthreads();
  if (tid == 0) {
    float s = 0.f;
    #pragma unroll
    for (int w = 0; w < WAVES; ++w) s += rsum[w];
    partial[b] = s;                                // plain store
  }
}

__global__ __launch_bounds__(256) void path_loss_reduce(
    const float* __restrict__ partial, float* __restrict__ out)
{
  __shared__ double rb[4];
  const int tid = threadIdx.x, lane = tid & 63, wid = tid >> 6;
  f4 v = ((const f4*)partial)[tid];                // 256*4 = 1024 floats
  double s = (double)v[0] + (double)v[1] + (double)v[2] + (double)v[3];
  #pragma unroll
  for (int d = 32; d > 0; d >>= 1) s += __shfl_down(s, d, 64);
  if (lane == 0) rb[wid] = s;
  __syncthreads();
  if (tid == 0) {
    double tot = rb[0] + rb[1] + rb[2] + rb[3];
    tot += (double)B_DIM * 1e-6;                   // t=0 column: sqrt(1e-12) per row
    out[0] = (float)(tot / ((double)B_DIM * (double)(T_DIM + 1)));
  }
}

extern "C" void kernel_launch(void* const* d_in, const int* in_sizes, int n_in,
                              void* d_out, int out_size, void* d_ws, size_t ws_size,
                              hipStream_t stream) {
  const float* outs   = (const float*)d_in[0];
  const int*   labels = (const int*)d_in[1];
  float* partial = (float*)d_ws;
  float* out     = (float*)d_out;

  path_loss_rows<<<B_DIM, NT, 0, stream>>>(outs, labels, partial);
  path_loss_reduce<<<1, 256, 0, stream>>>(partial, out);
}